// Round 3
// baseline (1598.747 us; speedup 1.0000x reference)
//
#include <hip/hip_runtime.h>
#include <math.h>

#define NN 50000
#define NE 800000
#define EAUG (NE + NN)
#define HD 128
#define NC 40
#define BN_EPS 1e-5f

// ---------------------------------------------------------------- utilities
static __device__ __forceinline__ float softplusf(float z) {
    if (z > 20.f) return z;
    if (z < -20.f) return expf(z);
    return log1pf(expf(z));
}

// ---------------------------------------------------------------- CSR build
__global__ __launch_bounds__(256) void hist_kernel(const int* __restrict__ ei,
                                                   int* __restrict__ cnt) {
    int e = blockIdx.x * 256 + threadIdx.x;
    if (e >= EAUG) return;
    int c = (e < NE) ? ei[NE + e] : (e - NE);
    atomicAdd(&cnt[c], 1);
}

__global__ __launch_bounds__(1024) void scan_kernel(const int* __restrict__ cnt,
                                                    int* __restrict__ off,
                                                    int* __restrict__ wp) {
    __shared__ int sdata[1024];
    __shared__ int carry;
    int tid = threadIdx.x;
    if (tid == 0) carry = 0;
    __syncthreads();
    for (int base = 0; base < NN; base += 1024) {
        int i = base + tid;
        int v = (i < NN) ? cnt[i] : 0;
        sdata[tid] = v;
        __syncthreads();
        for (int ofs = 1; ofs < 1024; ofs <<= 1) {
            int t = (tid >= ofs) ? sdata[tid - ofs] : 0;
            __syncthreads();
            sdata[tid] += t;
            __syncthreads();
        }
        int excl = sdata[tid] - v + carry;
        if (i < NN) { off[i] = excl; wp[i] = excl; }
        __syncthreads();
        if (tid == 1023) carry += sdata[1023];
        __syncthreads();
    }
    if (tid == 0) off[NN] = carry;   // == EAUG
}

__global__ __launch_bounds__(256) void scatter_kernel(const int* __restrict__ ei,
                                                      int* __restrict__ wp,
                                                      int* __restrict__ csr_e,
                                                      int* __restrict__ csr_s) {
    int e = blockIdx.x * 256 + threadIdx.x;
    if (e >= EAUG) return;
    int r, c;
    if (e < NE) { r = ei[e]; c = ei[NE + e]; } else { r = c = e - NE; }
    int pos = atomicAdd(&wp[c], 1);
    csr_e[pos] = e;
    csr_s[pos] = r;
}

// ---------------------------------------------------------------- fused GEMM: O_m = A @ W_m^T (+bias)
template <int NM>
__global__ __launch_bounds__(256) void gemm_nt(
    const float* __restrict__ A, int nrows,
    const float* __restrict__ W0, const float* __restrict__ B0, float* __restrict__ O0,
    const float* __restrict__ W1, const float* __restrict__ B1, float* __restrict__ O1,
    const float* __restrict__ W2, const float* __restrict__ B2, float* __restrict__ O2,
    const float* __restrict__ W3, const float* __restrict__ B3, float* __restrict__ O3) {
    __shared__ __align__(16) float xs[64 * HD];     // x tile [64][128]
    __shared__ __align__(16) float wsm[32 * HD];    // w chunk transposed [kk][c]
    const int t = threadIdx.x;
    const int r0 = blockIdx.x * 64;
    {
        const float4* A4 = (const float4*)A;
        float4* xs4 = (float4*)xs;
#pragma unroll
        for (int i = 0; i < 8; i++) {
            int idx = t + i * 256;
            int r = idx >> 5, q = idx & 31;
            float4 v = make_float4(0.f, 0.f, 0.f, 0.f);
            if (r0 + r < nrows) v = A4[(size_t)(r0 + r) * 32 + q];
            xs4[idx] = v;
        }
    }
    const int cg = t & 31, rg = t >> 5;
    const int c0 = cg * 4;
    const float* Ws[4] = {W0, W1, W2, W3};
    const float* Bs[4] = {B0, B1, B2, B3};
    float* Os[4] = {O0, O1, O2, O3};
#pragma unroll
    for (int m = 0; m < NM; m++) {
        float acc[8][4];
#pragma unroll
        for (int i = 0; i < 8; i++)
#pragma unroll
            for (int j = 0; j < 4; j++) acc[i][j] = 0.f;
        for (int kc = 0; kc < 4; kc++) {
            __syncthreads();
            const float4* Wm4 = (const float4*)Ws[m];
#pragma unroll
            for (int i = 0; i < 4; i++) {
                int idx = t + i * 256;           // 0..1023
                int c = idx >> 3, kq = idx & 7;  // c: 0..127, kq: 0..7
                float4 v = Wm4[(size_t)c * 32 + kc * 8 + kq];
                wsm[(kq * 4 + 0) * HD + c] = v.x;
                wsm[(kq * 4 + 1) * HD + c] = v.y;
                wsm[(kq * 4 + 2) * HD + c] = v.z;
                wsm[(kq * 4 + 3) * HD + c] = v.w;
            }
            __syncthreads();
#pragma unroll
            for (int kk = 0; kk < 32; kk += 4) {
                float4 wv0 = *(const float4*)&wsm[(kk + 0) * HD + c0];
                float4 wv1 = *(const float4*)&wsm[(kk + 1) * HD + c0];
                float4 wv2 = *(const float4*)&wsm[(kk + 2) * HD + c0];
                float4 wv3 = *(const float4*)&wsm[(kk + 3) * HD + c0];
#pragma unroll
                for (int i = 0; i < 8; i++) {
                    int r = rg * 8 + i;
                    float4 xv = *(const float4*)&xs[r * HD + kc * 32 + kk];
                    acc[i][0] += xv.x * wv0.x + xv.y * wv1.x + xv.z * wv2.x + xv.w * wv3.x;
                    acc[i][1] += xv.x * wv0.y + xv.y * wv1.y + xv.z * wv2.y + xv.w * wv3.y;
                    acc[i][2] += xv.x * wv0.z + xv.y * wv1.z + xv.z * wv2.z + xv.w * wv3.z;
                    acc[i][3] += xv.x * wv0.w + xv.y * wv1.w + xv.z * wv2.w + xv.w * wv3.w;
                }
            }
        }
        float4 bias = make_float4(0.f, 0.f, 0.f, 0.f);
        if (Bs[m]) bias = *(const float4*)&Bs[m][c0];
#pragma unroll
        for (int i = 0; i < 8; i++) {
            int r = r0 + rg * 8 + i;
            if (r < nrows) {
                float4 o;
                o.x = acc[i][0] + bias.x;
                o.y = acc[i][1] + bias.y;
                o.z = acc[i][2] + bias.z;
                o.w = acc[i][3] + bias.w;
                *(float4*)&Os[m][(size_t)r * HD + c0] = o;
            }
        }
    }
}

// ---------------------------------------------------------------- batchnorm
__global__ __launch_bounds__(256) void bn_reduce(const float* __restrict__ X,
                                                 float* __restrict__ sums) {
    int f = threadIdx.x & 127;
    int half = threadIdx.x >> 7;
    float s1 = 0.f, s2 = 0.f;
    for (int r = blockIdx.x * 2 + half; r < NN; r += gridDim.x * 2) {
        float v = X[(size_t)r * HD + f];
        s1 += v;
        s2 += v * v;
    }
    __shared__ float sm[512];
    sm[threadIdx.x] = s1;
    sm[256 + threadIdx.x] = s2;
    __syncthreads();
    if (half == 0) {
        atomicAdd(&sums[f], sm[f] + sm[128 + f]);
        atomicAdd(&sums[128 + f], sm[256 + f] + sm[256 + 128 + f]);
    }
}

__global__ __launch_bounds__(256) void bn_apply(const float* __restrict__ in,
                                                const float* __restrict__ sums,
                                                const float* __restrict__ gamma,
                                                const float* __restrict__ beta,
                                                const float* __restrict__ resid,
                                                float* __restrict__ out) {
    int idx = blockIdx.x * 256 + threadIdx.x;  // float4 index; total NN*32
    int f4 = idx & 31;
    float4 s1 = ((const float4*)sums)[f4];
    float4 s2 = ((const float4*)sums)[32 + f4];
    float4 g = ((const float4*)gamma)[f4];
    float4 bt = ((const float4*)beta)[f4];
    float4 v = ((const float4*)in)[idx];
    const float invn = 1.f / (float)NN;
    float4 o;
#define BN1(comp)                                                          \
    {                                                                      \
        float mean = s1.comp * invn;                                       \
        float var = s2.comp * invn - mean * mean;                          \
        float y = g.comp * (v.comp - mean) * rsqrtf(var + BN_EPS) + bt.comp; \
        o.comp = fmaxf(y, 0.f);                                            \
    }
    BN1(x) BN1(y) BN1(z) BN1(w)
#undef BN1
    if (resid) {
        float4 rv = ((const float4*)resid)[idx];
        o.x += rv.x; o.y += rv.y; o.z += rv.z; o.w += rv.w;
    }
    ((float4*)out)[idx] = o;
}

// ---------------------------------------------------------------- per-node dots: ar = xg . Wh[:128], ac = xg . Wh[128:]
__global__ __launch_bounds__(256) void node_dots(const float* __restrict__ xg,
                                                 const float* __restrict__ Wh,
                                                 float* __restrict__ ar,
                                                 float* __restrict__ ac) {
    int wid = (blockIdx.x * 256 + threadIdx.x) >> 6;
    int l = threadIdx.x & 63;
    if (wid >= NN) return;
    float2 xv = ((const float2*)(xg + (size_t)wid * HD))[l];
    float2 wa = ((const float2*)Wh)[l];
    float2 wb = ((const float2*)Wh)[64 + l];
    float pa = xv.x * wa.x + xv.y * wa.y;
    float pb = xv.x * wb.x + xv.y * wb.y;
#pragma unroll
    for (int ofs = 1; ofs < 64; ofs <<= 1) {
        pa += __shfl_xor(pa, ofs);
        pb += __shfl_xor(pb, ofs);
    }
    if (l == 0) { ar[wid] = pa; ac[wid] = pb; }
}

// ---------------------------------------------------------------- edge pass: s_ij -> exp terms + z sums
__global__ __launch_bounds__(256) void edge_pass(const float* __restrict__ xg,
                                                 const float* __restrict__ ar,
                                                 const float* __restrict__ ac,
                                                 const int* __restrict__ ei,
                                                 const float* __restrict__ bh,
                                                 float* __restrict__ econ,
                                                 float* __restrict__ edis,
                                                 float* __restrict__ zcon,
                                                 float* __restrict__ zdis) {
    int gid = blockIdx.x * 256 + threadIdx.x;
    int e = gid >> 4;   // 16 lanes per edge
    int l = gid & 15;
    if (e >= EAUG) return;
    int r, c;
    if (e < NE) { r = ei[e]; c = ei[NE + e]; } else { r = c = e - NE; }
    const float4* xr4 = (const float4*)(xg + (size_t)r * HD);
    const float4* xc4 = (const float4*)(xg + (size_t)c * HD);
    float4 a0 = xr4[l], a1 = xr4[16 + l];
    float4 b0 = xc4[l], b1 = xc4[16 + l];
    float d, ss = 0.f;
    d = a0.x - b0.x; ss += d * d;
    d = a0.y - b0.y; ss += d * d;
    d = a0.z - b0.z; ss += d * d;
    d = a0.w - b0.w; ss += d * d;
    d = a1.x - b1.x; ss += d * d;
    d = a1.y - b1.y; ss += d * d;
    d = a1.z - b1.z; ss += d * d;
    d = a1.w - b1.w; ss += d * d;
#pragma unroll
    for (int ofs = 1; ofs < 16; ofs <<= 1) ss += __shfl_xor(ss, ofs);
    if (l == 0) {
        float g = sqrtf(ss + 1e-12f);
        float hh = softplusf(ar[r] + ac[c] + bh[0]);
        float tt = g + hh;                       // >= 0
        float s = 1.f / (1.f + expf(tt));        // sigmoid(-t), in (0, 0.5]
        float ec = expf(s);
        float ed = expf(1.f - s);
        econ[e] = ec;
        edis[e] = ed;
        atomicAdd(&zcon[r], ec);
        atomicAdd(&zdis[r], ed);
    }
}

__global__ __launch_bounds__(256) void normalize_w(const int* __restrict__ ei,
                                                   const float* __restrict__ zcon,
                                                   const float* __restrict__ zdis,
                                                   float* __restrict__ econ,
                                                   float* __restrict__ edis) {
    int e = blockIdx.x * 256 + threadIdx.x;
    if (e >= EAUG) return;
    int r = (e < NE) ? ei[e] : (e - NE);
    econ[e] = econ[e] / zcon[r];
    edis[e] = edis[e] / zdis[r];
}

// ---------------------------------------------------------------- aggregation + gating (+optional residual)
__global__ __launch_bounds__(256) void agg_gate(const float* __restrict__ xcon,
                                                const float* __restrict__ xdis,
                                                const float* __restrict__ xself,
                                                const float* __restrict__ econ,
                                                const float* __restrict__ edis,
                                                const int* __restrict__ coff,
                                                const int* __restrict__ csr_e,
                                                const int* __restrict__ csr_s,
                                                const float* __restrict__ Wgate,
                                                const float* __restrict__ bgate,
                                                const float* __restrict__ resid,
                                                float* __restrict__ out) {
    int v = (blockIdx.x * 256 + threadIdx.x) >> 6;
    int l = threadIdx.x & 63;
    if (v >= NN) return;
    int beg = coff[v], end = coff[v + 1];
    float cx = 0.f, cy = 0.f, dxv = 0.f, dyv = 0.f;
    for (int j = beg; j < end; j++) {
        int eid = csr_e[j];
        int r = csr_s[j];
        float wc = econ[eid], wd = edis[eid];
        float2 a = ((const float2*)(xcon + (size_t)r * HD))[l];
        float2 b = ((const float2*)(xdis + (size_t)r * HD))[l];
        cx += wc * a.x; cy += wc * a.y;
        dxv += wd * b.x; dyv += wd * b.y;
    }
    float2 sf = ((const float2*)(xself + (size_t)v * HD))[l];
    // gate logits: 3 dots over 384 features
    float p[3];
#pragma unroll
    for (int i = 0; i < 3; i++) {
        float2 wa = ((const float2*)(Wgate + i * 384))[l];
        float2 wb = ((const float2*)(Wgate + i * 384 + 128))[l];
        float2 wc2 = ((const float2*)(Wgate + i * 384 + 256))[l];
        p[i] = wa.x * cx + wa.y * cy + wb.x * dxv + wb.y * dyv + wc2.x * sf.x + wc2.y * sf.y;
    }
#pragma unroll
    for (int ofs = 1; ofs < 64; ofs <<= 1) {
        p[0] += __shfl_xor(p[0], ofs);
        p[1] += __shfl_xor(p[1], ofs);
        p[2] += __shfl_xor(p[2], ofs);
    }
    float l0 = p[0] + bgate[0], l1 = p[1] + bgate[1], l2 = p[2] + bgate[2];
    float mx = fmaxf(l0, fmaxf(l1, l2));
    float e0 = expf(l0 - mx), e1 = expf(l1 - mx), e2 = expf(l2 - mx);
    float inv = 1.f / (e0 + e1 + e2);
    float g0 = e0 * inv, g1 = e1 * inv, g2 = e2 * inv;
    float2 o;
    o.x = g0 * cx + g1 * dxv + g2 * sf.x;
    o.y = g0 * cy + g1 * dyv + g2 * sf.y;
    if (resid) {
        float2 rv = ((const float2*)(resid + (size_t)v * HD))[l];
        o.x += rv.x; o.y += rv.y;
    }
    ((float2*)(out + (size_t)v * HD))[l] = o;
}

// ---------------------------------------------------------------- classifier: out = X @ clsW^T + b  ([N,128]x[40,128])
__global__ __launch_bounds__(256) void cls_gemm(const float* __restrict__ X,
                                                const float* __restrict__ W,
                                                const float* __restrict__ b,
                                                float* __restrict__ out) {
    int wid = (blockIdx.x * 256 + threadIdx.x) >> 6;
    int l = threadIdx.x & 63;
    if (wid >= NN) return;
    float2 xv = ((const float2*)(X + (size_t)wid * HD))[l];
    float keep = 0.f;
#pragma unroll
    for (int c = 0; c < NC; c++) {
        float2 wv = ((const float2*)(W + (size_t)c * HD))[l];
        float pp = xv.x * wv.x + xv.y * wv.y;
#pragma unroll
        for (int ofs = 1; ofs < 64; ofs <<= 1) pp += __shfl_xor(pp, ofs);
        if (l == c) keep = pp;
    }
    if (l < NC) out[(size_t)wid * NC + l] = keep + b[l];
}

// ---------------------------------------------------------------- launcher
extern "C" void kernel_launch(void* const* d_in, const int* in_sizes, int n_in,
                              void* d_out, int out_size, void* d_ws, size_t ws_size,
                              hipStream_t stream) {
    const float* x = (const float*)d_in[0];
    const int* ei = (const int*)d_in[1];
    const float* mlp_W = (const float*)d_in[2];
    const float* mlp_b = (const float*)d_in[3];
    const float* mlp_gamma = (const float*)d_in[4];
    const float* mlp_beta = (const float*)d_in[5];
    const float* bn0_gamma = (const float*)d_in[6];
    const float* bn0_beta = (const float*)d_in[7];
    const float* cls_W = (const float*)d_in[8];
    const float* cls_b = (const float*)d_in[9];

    const size_t NF = (size_t)NN * HD;
    float* ws = (float*)d_ws;
    float* raw = ws;              // conv raw (layer0) / x2 (layer1)
    float* h0 = ws + NF;
    float* x1 = ws + 2 * NF;
    float* xg = ws + 3 * NF;
    float* xcon = ws + 4 * NF;
    float* xdis = ws + 5 * NF;
    float* xself = ws + 6 * NF;
    float* ar = ws + 7 * NF;
    float* ac = ar + NN;
    float* econ = ac + NN;
    float* edis = econ + EAUG;
    float* zcon = edis + EAUG;
    float* zdis = zcon + NN;
    float* bnsums = zdis + NN;             // 256
    int* cnt = (int*)(bnsums + 256);       // NN
    int* coff = cnt + NN;                  // NN+1
    int* wp = coff + NN + 1;               // NN
    int* csr_e = wp + NN;                  // EAUG
    int* csr_s = csr_e + EAUG;             // EAUG

    const int EB = (EAUG + 255) / 256;     // 3321
    const int GB = (NN + 63) / 64;         // 782
    const int WB = NN / 4;                 // 12500 (wave-per-node kernels)
    const int EDGEB = EAUG * 16 / 256;     // 53125

    // ---- CSR by col (rebuilt every call; no persistent state allowed)
    hipMemsetAsync(cnt, 0, NN * sizeof(int), stream);
    hist_kernel<<<EB, 256, 0, stream>>>(ei, cnt);
    scan_kernel<<<1, 1024, 0, stream>>>(cnt, coff, wp);
    scatter_kernel<<<EB, 256, 0, stream>>>(ei, wp, csr_e, csr_s);

    // ---- input MLP + BN + relu
    gemm_nt<1><<<GB, 256, 0, stream>>>(x, NN, mlp_W, mlp_b, raw,
                                       nullptr, nullptr, nullptr,
                                       nullptr, nullptr, nullptr,
                                       nullptr, nullptr, nullptr);
    hipMemsetAsync(bnsums, 0, 256 * sizeof(float), stream);
    bn_reduce<<<256, 256, 0, stream>>>(raw, bnsums);
    bn_apply<<<(int)(NF / 4 / 256), 256, 0, stream>>>(raw, bnsums, mlp_gamma, mlp_beta,
                                                      nullptr, h0);

    for (int layer = 0; layer < 2; layer++) {
        const float* Wg = (const float*)d_in[10 + layer * 9 + 0];
        const float* Wh = (const float*)d_in[10 + layer * 9 + 1];
        const float* bh = (const float*)d_in[10 + layer * 9 + 2];
        const float* Wcon = (const float*)d_in[10 + layer * 9 + 3];
        const float* Wdis = (const float*)d_in[10 + layer * 9 + 4];
        const float* Wself = (const float*)d_in[10 + layer * 9 + 5];
        const float* bself = (const float*)d_in[10 + layer * 9 + 6];
        const float* Wgate = (const float*)d_in[10 + layer * 9 + 7];
        const float* bgate = (const float*)d_in[10 + layer * 9 + 8];
        const float* hin = (layer == 0) ? h0 : x1;

        gemm_nt<4><<<GB, 256, 0, stream>>>(hin, NN,
                                           Wg, nullptr, xg,
                                           Wcon, nullptr, xcon,
                                           Wdis, nullptr, xdis,
                                           Wself, bself, xself);
        node_dots<<<WB, 256, 0, stream>>>(xg, Wh, ar, ac);
        hipMemsetAsync(zcon, 0, NN * sizeof(float), stream);
        hipMemsetAsync(zdis, 0, NN * sizeof(float), stream);
        edge_pass<<<EDGEB, 256, 0, stream>>>(xg, ar, ac, ei, bh, econ, edis, zcon, zdis);
        normalize_w<<<EB, 256, 0, stream>>>(ei, zcon, zdis, econ, edis);
        if (layer == 0) {
            agg_gate<<<WB, 256, 0, stream>>>(xcon, xdis, xself, econ, edis, coff, csr_e,
                                             csr_s, Wgate, bgate, nullptr, raw);
            hipMemsetAsync(bnsums, 0, 256 * sizeof(float), stream);
            bn_reduce<<<256, 256, 0, stream>>>(raw, bnsums);
            bn_apply<<<(int)(NF / 4 / 256), 256, 0, stream>>>(raw, bnsums, bn0_gamma,
                                                              bn0_beta, h0, x1);
        } else {
            // x2 = gated + x1, stored into raw (reused)
            agg_gate<<<WB, 256, 0, stream>>>(xcon, xdis, xself, econ, edis, coff, csr_e,
                                             csr_s, Wgate, bgate, x1, raw);
        }
    }

    // ---- classifier
    cls_gemm<<<WB, 256, 0, stream>>>(raw, cls_W, cls_b, (float*)d_out);
}

// Round 7
// 1224.436 us; speedup vs baseline: 1.3057x; 1.3057x over previous
//
#include <hip/hip_runtime.h>
#include <math.h>

#define NN 50000
#define NE 800000
#define EAUG (NE + NN)
#define HD 128
#define NC 40
#define BN_EPS 1e-5f
#define LDA 136  // padded LDS stride (elems): 272B/row -> 2-way bank aliasing (free)

typedef short bf16x8 __attribute__((ext_vector_type(8)));
typedef float f32x4 __attribute__((ext_vector_type(4)));

// ---------------------------------------------------------------- utilities
static __device__ __forceinline__ float softplusf(float z) {
    if (z > 20.f) return z;
    if (z < -20.f) return expf(z);
    return log1pf(expf(z));
}

static __device__ __forceinline__ unsigned short f2bf(float f) {
    union { float f; unsigned int u; } v;
    v.f = f;
    unsigned int u = v.u;
    unsigned int r = (u + 0x7fffu + ((u >> 16) & 1u)) >> 16;
    return (unsigned short)r;
}

// ---------------------------------------------------------------- CSR build
__global__ __launch_bounds__(256) void hist_kernel(const int* __restrict__ ei,
                                                   int* __restrict__ cnt) {
    int e = blockIdx.x * 256 + threadIdx.x;
    if (e >= EAUG) return;
    int c = (e < NE) ? ei[NE + e] : (e - NE);
    atomicAdd(&cnt[c], 1);
}

__global__ __launch_bounds__(1024) void scan_kernel(const int* __restrict__ cnt,
                                                    int* __restrict__ off,
                                                    int* __restrict__ wp) {
    __shared__ int sdata[1024];
    __shared__ int carry;
    int tid = threadIdx.x;
    if (tid == 0) carry = 0;
    __syncthreads();
    for (int base = 0; base < NN; base += 1024) {
        int i = base + tid;
        int v = (i < NN) ? cnt[i] : 0;
        sdata[tid] = v;
        __syncthreads();
        for (int ofs = 1; ofs < 1024; ofs <<= 1) {
            int t = (tid >= ofs) ? sdata[tid - ofs] : 0;
            __syncthreads();
            sdata[tid] += t;
            __syncthreads();
        }
        int excl = sdata[tid] - v + carry;
        if (i < NN) { off[i] = excl; wp[i] = excl; }
        __syncthreads();
        if (tid == 1023) carry += sdata[1023];
        __syncthreads();
    }
    if (tid == 0) off[NN] = carry;   // == EAUG
}

__global__ __launch_bounds__(256) void scatter_kernel(const int* __restrict__ ei,
                                                      int* __restrict__ wp,
                                                      int* __restrict__ csr_e,
                                                      int* __restrict__ csr_s) {
    int e = blockIdx.x * 256 + threadIdx.x;
    if (e >= EAUG) return;
    int r, c;
    if (e < NE) { r = ei[e]; c = ei[NE + e]; } else { r = c = e - NE; }
    int pos = atomicAdd(&wp[c], 1);
    csr_e[pos] = e;
    csr_s[pos] = r;
}

// ---------------------------------------------------------------- MFMA GEMM: O_m = A @ W_m^T (+bias)
// A [nrows][128] fp32 (converted to bf16 in staging), W [128][128] fp32.
// Block: 64 rows x 128 cols, 256 threads = 4 waves; wave w -> rows 16w..16w+15.
template <int NM>
__global__ __launch_bounds__(256) void gemm_mfma(
    const float* __restrict__ A, int nrows,
    const float* __restrict__ W0, const float* __restrict__ B0, float* __restrict__ O0,
    const float* __restrict__ W1, const float* __restrict__ B1, float* __restrict__ O1,
    const float* __restrict__ W2, const float* __restrict__ B2, float* __restrict__ O2,
    const float* __restrict__ W3, const float* __restrict__ B3, float* __restrict__ O3) {
    __shared__ __align__(16) unsigned short As[64 * LDA];
    __shared__ __align__(16) unsigned short Bs_lds[128 * LDA];
    const int t = threadIdx.x;
    const int r0 = blockIdx.x * 64;

    // ---- stage A tile (fp32 -> bf16), rows r0..r0+63
    {
        const float4* A4 = (const float4*)A;
#pragma unroll
        for (int i = 0; i < 8; i++) {
            int f4 = t + i * 256;          // 0..2047
            int row = f4 >> 5;             // 0..63
            int q = f4 & 31;               // float4 within row
            float4 v = make_float4(0.f, 0.f, 0.f, 0.f);
            if (r0 + row < nrows) v = A4[(size_t)(r0 + row) * 32 + q];
            ushort4 b;
            b.x = f2bf(v.x); b.y = f2bf(v.y); b.z = f2bf(v.z); b.w = f2bf(v.w);
            *(ushort4*)&As[row * LDA + q * 4] = b;
        }
    }

    const float* Ws[4] = {W0, W1, W2, W3};
    const float* Bb[4] = {B0, B1, B2, B3};
    float* Os[4] = {O0, O1, O2, O3};
    const int wv = t >> 6;          // wave 0..3
    const int ln = t & 63;
    const int lrow = ln & 15;       // row/col within 16
    const int lk = ln >> 4;         // k-group 0..3

#pragma unroll
    for (int m = 0; m < NM; m++) {
        __syncthreads();            // Bs_lds safe to overwrite / As ready
        {
            const float4* Wm4 = (const float4*)Ws[m];
#pragma unroll
            for (int i = 0; i < 16; i++) {
                int f4 = t + i * 256;      // 0..4095
                int c = f4 >> 5;           // 0..127 (output col = W row)
                int q = f4 & 31;
                float4 v = Wm4[f4];
                ushort4 b;
                b.x = f2bf(v.x); b.y = f2bf(v.y); b.z = f2bf(v.z); b.w = f2bf(v.w);
                *(ushort4*)&Bs_lds[c * LDA + q * 4] = b;
            }
        }
        __syncthreads();

        f32x4 acc[8];
#pragma unroll
        for (int nt = 0; nt < 8; nt++) acc[nt] = (f32x4){0.f, 0.f, 0.f, 0.f};

#pragma unroll
        for (int ks = 0; ks < 4; ks++) {
            int kb = ks * 32 + lk * 8;
            bf16x8 af = *(const bf16x8*)&As[(wv * 16 + lrow) * LDA + kb];
#pragma unroll
            for (int nt = 0; nt < 8; nt++) {
                bf16x8 bfr = *(const bf16x8*)&Bs_lds[(nt * 16 + lrow) * LDA + kb];
                acc[nt] = __builtin_amdgcn_mfma_f32_16x16x32_bf16(af, bfr, acc[nt], 0, 0, 0);
            }
        }

        // ---- epilogue: C layout col=lane&15, row=(lane>>4)*4+j
        const float* bias = Bb[m];
#pragma unroll
        for (int nt = 0; nt < 8; nt++) {
            int col = nt * 16 + lrow;
            float bv = bias ? bias[col] : 0.f;
#pragma unroll
            for (int j = 0; j < 4; j++) {
                int row = r0 + wv * 16 + lk * 4 + j;
                if (row < nrows) Os[m][(size_t)row * HD + col] = acc[nt][j] + bv;
            }
        }
    }
}

// ---------------------------------------------------------------- batchnorm
__global__ __launch_bounds__(256) void bn_reduce(const float* __restrict__ X,
                                                 float* __restrict__ sums) {
    int f = threadIdx.x & 127;
    int half = threadIdx.x >> 7;
    float s1 = 0.f, s2 = 0.f;
    for (int r = blockIdx.x * 2 + half; r < NN; r += gridDim.x * 2) {
        float v = X[(size_t)r * HD + f];
        s1 += v;
        s2 += v * v;
    }
    __shared__ float sm[512];
    sm[threadIdx.x] = s1;
    sm[256 + threadIdx.x] = s2;
    __syncthreads();
    if (half == 0) {
        atomicAdd(&sums[f], sm[f] + sm[128 + f]);
        atomicAdd(&sums[128 + f], sm[256 + f] + sm[256 + 128 + f]);
    }
}

__global__ __launch_bounds__(256) void bn_apply(const float* __restrict__ in,
                                                const float* __restrict__ sums,
                                                const float* __restrict__ gamma,
                                                const float* __restrict__ beta,
                                                const float* __restrict__ resid,
                                                float* __restrict__ out) {
    int idx = blockIdx.x * 256 + threadIdx.x;  // float4 index; total NN*32
    int f4 = idx & 31;
    float4 s1 = ((const float4*)sums)[f4];
    float4 s2 = ((const float4*)sums)[32 + f4];
    float4 g = ((const float4*)gamma)[f4];
    float4 bt = ((const float4*)beta)[f4];
    float4 v = ((const float4*)in)[idx];
    const float invn = 1.f / (float)NN;
    float4 o;
#define BN1(comp)                                                          \
    {                                                                      \
        float mean = s1.comp * invn;                                       \
        float var = s2.comp * invn - mean * mean;                          \
        float y = g.comp * (v.comp - mean) * rsqrtf(var + BN_EPS) + bt.comp; \
        o.comp = fmaxf(y, 0.f);                                            \
    }
    BN1(x) BN1(y) BN1(z) BN1(w)
#undef BN1
    if (resid) {
        float4 rv = ((const float4*)resid)[idx];
        o.x += rv.x; o.y += rv.y; o.z += rv.z; o.w += rv.w;
    }
    ((float4*)out)[idx] = o;
}

// ---------------------------------------------------------------- per-node dots: ar = xg . Wh[:128], ac = xg . Wh[128:]
__global__ __launch_bounds__(256) void node_dots(const float* __restrict__ xg,
                                                 const float* __restrict__ Wh,
                                                 float* __restrict__ ar,
                                                 float* __restrict__ ac) {
    int wid = (blockIdx.x * 256 + threadIdx.x) >> 6;
    int l = threadIdx.x & 63;
    if (wid >= NN) return;
    float2 xv = ((const float2*)(xg + (size_t)wid * HD))[l];
    float2 wa = ((const float2*)Wh)[l];
    float2 wb = ((const float2*)Wh)[64 + l];
    float pa = xv.x * wa.x + xv.y * wa.y;
    float pb = xv.x * wb.x + xv.y * wb.y;
#pragma unroll
    for (int ofs = 1; ofs < 64; ofs <<= 1) {
        pa += __shfl_xor(pa, ofs);
        pb += __shfl_xor(pb, ofs);
    }
    if (l == 0) { ar[wid] = pa; ac[wid] = pb; }
}

// ---------------------------------------------------------------- edge pass: s_ij -> exp terms + z sums
__global__ __launch_bounds__(256) void edge_pass(const float* __restrict__ xg,
                                                 const float* __restrict__ ar,
                                                 const float* __restrict__ ac,
                                                 const int* __restrict__ ei,
                                                 const float* __restrict__ bh,
                                                 float* __restrict__ econ,
                                                 float* __restrict__ edis,
                                                 float* __restrict__ zcon,
                                                 float* __restrict__ zdis) {
    int gid = blockIdx.x * 256 + threadIdx.x;
    int e = gid >> 4;   // 16 lanes per edge
    int l = gid & 15;
    if (e >= EAUG) return;
    int r, c;
    if (e < NE) { r = ei[e]; c = ei[NE + e]; } else { r = c = e - NE; }
    const float4* xr4 = (const float4*)(xg + (size_t)r * HD);
    const float4* xc4 = (const float4*)(xg + (size_t)c * HD);
    float4 a0 = xr4[l], a1 = xr4[16 + l];
    float4 b0 = xc4[l], b1 = xc4[16 + l];
    float d, ss = 0.f;
    d = a0.x - b0.x; ss += d * d;
    d = a0.y - b0.y; ss += d * d;
    d = a0.z - b0.z; ss += d * d;
    d = a0.w - b0.w; ss += d * d;
    d = a1.x - b1.x; ss += d * d;
    d = a1.y - b1.y; ss += d * d;
    d = a1.z - b1.z; ss += d * d;
    d = a1.w - b1.w; ss += d * d;
#pragma unroll
    for (int ofs = 1; ofs < 16; ofs <<= 1) ss += __shfl_xor(ss, ofs);
    if (l == 0) {
        float g = sqrtf(ss + 1e-12f);
        float hh = softplusf(ar[r] + ac[c] + bh[0]);
        float tt = g + hh;                       // >= 0
        float s = 1.f / (1.f + expf(tt));        // sigmoid(-t), in (0, 0.5]
        float ec = expf(s);
        float ed = expf(1.f - s);
        econ[e] = ec;
        edis[e] = ed;
        atomicAdd(&zcon[r], ec);
        atomicAdd(&zdis[r], ed);
    }
}

// ---------------------------------------------------------------- aggregation + gating (+optional residual)
// softmax normalization fused: w = e[eid] / z[src]
__global__ __launch_bounds__(256) void agg_gate(const float* __restrict__ xcon,
                                                const float* __restrict__ xdis,
                                                const float* __restrict__ xself,
                                                const float* __restrict__ econ,
                                                const float* __restrict__ edis,
                                                const float* __restrict__ zcon,
                                                const float* __restrict__ zdis,
                                                const int* __restrict__ coff,
                                                const int* __restrict__ csr_e,
                                                const int* __restrict__ csr_s,
                                                const float* __restrict__ Wgate,
                                                const float* __restrict__ bgate,
                                                const float* __restrict__ resid,
                                                float* __restrict__ out) {
    int v = (blockIdx.x * 256 + threadIdx.x) >> 6;
    int l = threadIdx.x & 63;
    if (v >= NN) return;
    int beg = coff[v], end = coff[v + 1];
    float cx = 0.f, cy = 0.f, dxv = 0.f, dyv = 0.f;
    for (int j = beg; j < end; j++) {
        int eid = csr_e[j];
        int r = csr_s[j];
        float wc = econ[eid] / zcon[r];
        float wd = edis[eid] / zdis[r];
        float2 a = ((const float2*)(xcon + (size_t)r * HD))[l];
        float2 b = ((const float2*)(xdis + (size_t)r * HD))[l];
        cx += wc * a.x; cy += wc * a.y;
        dxv += wd * b.x; dyv += wd * b.y;
    }
    float2 sf = ((const float2*)(xself + (size_t)v * HD))[l];
    // gate logits: 3 dots over 384 features
    float p[3];
#pragma unroll
    for (int i = 0; i < 3; i++) {
        float2 wa = ((const float2*)(Wgate + i * 384))[l];
        float2 wb = ((const float2*)(Wgate + i * 384 + 128))[l];
        float2 wc2 = ((const float2*)(Wgate + i * 384 + 256))[l];
        p[i] = wa.x * cx + wa.y * cy + wb.x * dxv + wb.y * dyv + wc2.x * sf.x + wc2.y * sf.y;
    }
#pragma unroll
    for (int ofs = 1; ofs < 64; ofs <<= 1) {
        p[0] += __shfl_xor(p[0], ofs);
        p[1] += __shfl_xor(p[1], ofs);
        p[2] += __shfl_xor(p[2], ofs);
    }
    float l0 = p[0] + bgate[0], l1 = p[1] + bgate[1], l2 = p[2] + bgate[2];
    float mx = fmaxf(l0, fmaxf(l1, l2));
    float e0 = expf(l0 - mx), e1 = expf(l1 - mx), e2 = expf(l2 - mx);
    float inv = 1.f / (e0 + e1 + e2);
    float g0 = e0 * inv, g1 = e1 * inv, g2 = e2 * inv;
    float2 o;
    o.x = g0 * cx + g1 * dxv + g2 * sf.x;
    o.y = g0 * cy + g1 * dyv + g2 * sf.y;
    if (resid) {
        float2 rv = ((const float2*)(resid + (size_t)v * HD))[l];
        o.x += rv.x; o.y += rv.y;
    }
    ((float2*)(out + (size_t)v * HD))[l] = o;
}

// ---------------------------------------------------------------- classifier: out = X @ clsW^T + b  ([N,128]x[40,128])
__global__ __launch_bounds__(256) void cls_gemm(const float* __restrict__ X,
                                                const float* __restrict__ W,
                                                const float* __restrict__ b,
                                                float* __restrict__ out) {
    int wid = (blockIdx.x * 256 + threadIdx.x) >> 6;
    int l = threadIdx.x & 63;
    if (wid >= NN) return;
    float2 xv = ((const float2*)(X + (size_t)wid * HD))[l];
    float keep = 0.f;
#pragma unroll
    for (int c = 0; c < NC; c++) {
        float2 wv = ((const float2*)(W + (size_t)c * HD))[l];
        float pp = xv.x * wv.x + xv.y * wv.y;
#pragma unroll
        for (int ofs = 1; ofs < 64; ofs <<= 1) pp += __shfl_xor(pp, ofs);
        if (l == c) keep = pp;
    }
    if (l < NC) out[(size_t)wid * NC + l] = keep + b[l];
}

// ---------------------------------------------------------------- launcher
extern "C" void kernel_launch(void* const* d_in, const int* in_sizes, int n_in,
                              void* d_out, int out_size, void* d_ws, size_t ws_size,
                              hipStream_t stream) {
    const float* x = (const float*)d_in[0];
    const int* ei = (const int*)d_in[1];
    const float* mlp_W = (const float*)d_in[2];
    const float* mlp_b = (const float*)d_in[3];
    const float* mlp_gamma = (const float*)d_in[4];
    const float* mlp_beta = (const float*)d_in[5];
    const float* bn0_gamma = (const float*)d_in[6];
    const float* bn0_beta = (const float*)d_in[7];
    const float* cls_W = (const float*)d_in[8];
    const float* cls_b = (const float*)d_in[9];

    const size_t NF = (size_t)NN * HD;
    float* ws = (float*)d_ws;
    float* raw = ws;              // conv raw (layer0) / x2 (layer1)
    float* h0 = ws + NF;
    float* x1 = ws + 2 * NF;
    float* xg = ws + 3 * NF;
    float* xcon = ws + 4 * NF;
    float* xdis = ws + 5 * NF;
    float* xself = ws + 6 * NF;
    float* ar = ws + 7 * NF;
    float* ac = ar + NN;
    float* econ = ac + NN;
    float* edis = econ + EAUG;
    float* zcon = edis + EAUG;
    float* zdis = zcon + NN;
    float* bnsums = zdis + NN;             // 256
    int* cnt = (int*)(bnsums + 256);       // NN
    int* coff = cnt + NN;                  // NN+1
    int* wp = coff + NN + 1;               // NN
    int* csr_e = wp + NN;                  // EAUG
    int* csr_s = csr_e + EAUG;             // EAUG

    const int EB = (EAUG + 255) / 256;     // 3321
    const int GB = (NN + 63) / 64;         // 782
    const int WB = NN / 4;                 // 12500 (wave-per-node kernels)
    const int EDGEB = EAUG * 16 / 256;     // 53125

    // ---- CSR by col (rebuilt every call; no persistent state allowed)
    hipMemsetAsync(cnt, 0, NN * sizeof(int), stream);
    hist_kernel<<<EB, 256, 0, stream>>>(ei, cnt);
    scan_kernel<<<1, 1024, 0, stream>>>(cnt, coff, wp);
    scatter_kernel<<<EB, 256, 0, stream>>>(ei, wp, csr_e, csr_s);

    // ---- input MLP + BN + relu
    gemm_mfma<1><<<GB, 256, 0, stream>>>(x, NN, mlp_W, mlp_b, raw,
                                         nullptr, nullptr, nullptr,
                                         nullptr, nullptr, nullptr,
                                         nullptr, nullptr, nullptr);
    hipMemsetAsync(bnsums, 0, 256 * sizeof(float), stream);
    bn_reduce<<<256, 256, 0, stream>>>(raw, bnsums);
    bn_apply<<<(int)(NF / 4 / 256), 256, 0, stream>>>(raw, bnsums, mlp_gamma, mlp_beta,
                                                      nullptr, h0);

    for (int layer = 0; layer < 2; layer++) {
        const float* Wg = (const float*)d_in[10 + layer * 9 + 0];
        const float* Wh = (const float*)d_in[10 + layer * 9 + 1];
        const float* bh = (const float*)d_in[10 + layer * 9 + 2];
        const float* Wcon = (const float*)d_in[10 + layer * 9 + 3];
        const float* Wdis = (const float*)d_in[10 + layer * 9 + 4];
        const float* Wself = (const float*)d_in[10 + layer * 9 + 5];
        const float* bself = (const float*)d_in[10 + layer * 9 + 6];
        const float* Wgate = (const float*)d_in[10 + layer * 9 + 7];
        const float* bgate = (const float*)d_in[10 + layer * 9 + 8];
        const float* hin = (layer == 0) ? h0 : x1;

        gemm_mfma<4><<<GB, 256, 0, stream>>>(hin, NN,
                                             Wg, nullptr, xg,
                                             Wcon, nullptr, xcon,
                                             Wdis, nullptr, xdis,
                                             Wself, bself, xself);
        node_dots<<<WB, 256, 0, stream>>>(xg, Wh, ar, ac);
        hipMemsetAsync(zcon, 0, NN * sizeof(float), stream);
        hipMemsetAsync(zdis, 0, NN * sizeof(float), stream);
        edge_pass<<<EDGEB, 256, 0, stream>>>(xg, ar, ac, ei, bh, econ, edis, zcon, zdis);
        if (layer == 0) {
            agg_gate<<<WB, 256, 0, stream>>>(xcon, xdis, xself, econ, edis, zcon, zdis,
                                             coff, csr_e, csr_s, Wgate, bgate, nullptr, raw);
            hipMemsetAsync(bnsums, 0, 256 * sizeof(float), stream);
            bn_reduce<<<256, 256, 0, stream>>>(raw, bnsums);
            bn_apply<<<(int)(NF / 4 / 256), 256, 0, stream>>>(raw, bnsums, bn0_gamma,
                                                              bn0_beta, h0, x1);
        } else {
            // x2 = gated + x1, stored into raw (reused)
            agg_gate<<<WB, 256, 0, stream>>>(xcon, xdis, xself, econ, edis, zcon, zdis,
                                             coff, csr_e, csr_s, Wgate, bgate, x1, raw);
        }
    }

    // ---- classifier
    cls_gemm<<<WB, 256, 0, stream>>>(raw, cls_W, cls_b, (float*)d_out);
}

// Round 8
// 1103.562 us; speedup vs baseline: 1.4487x; 1.1095x over previous
//
#include <hip/hip_runtime.h>
#include <math.h>

#define NN 50000
#define NE 800000
#define EAUG (NE + NN)
#define HD 128
#define NC 40
#define BN_EPS 1e-5f
#define LDA 136  // padded LDS stride (elems): 272B/row -> 2-way bank aliasing (free)

typedef short bf16x8 __attribute__((ext_vector_type(8)));
typedef float f32x4 __attribute__((ext_vector_type(4)));
typedef unsigned short ushort_t;

// ---------------------------------------------------------------- utilities
static __device__ __forceinline__ float softplusf(float z) {
    if (z > 20.f) return z;
    if (z < -20.f) return expf(z);
    return log1pf(expf(z));
}

static __device__ __forceinline__ unsigned short f2bf(float f) {
    union { float f; unsigned int u; } v;
    v.f = f;
    unsigned int u = v.u;
    unsigned int r = (u + 0x7fffu + ((u >> 16) & 1u)) >> 16;
    return (unsigned short)r;
}
static __device__ __forceinline__ float b2f_lo(unsigned int u) {
    union { unsigned int i; float f; } v; v.i = u << 16; return v.f;
}
static __device__ __forceinline__ float b2f_hi(unsigned int u) {
    union { unsigned int i; float f; } v; v.i = u & 0xffff0000u; return v.f;
}

// ---------------------------------------------------------------- CSR build
__global__ __launch_bounds__(256) void hist_kernel(const int* __restrict__ ei,
                                                   int* __restrict__ cnt) {
    int e = blockIdx.x * 256 + threadIdx.x;
    if (e >= EAUG) return;
    int c = (e < NE) ? ei[NE + e] : (e - NE);
    atomicAdd(&cnt[c], 1);
}

__global__ __launch_bounds__(1024) void scan_kernel(const int* __restrict__ cnt,
                                                    int* __restrict__ off,
                                                    int* __restrict__ wp) {
    __shared__ int sdata[1024];
    __shared__ int carry;
    int tid = threadIdx.x;
    if (tid == 0) carry = 0;
    __syncthreads();
    for (int base = 0; base < NN; base += 1024) {
        int i = base + tid;
        int v = (i < NN) ? cnt[i] : 0;
        sdata[tid] = v;
        __syncthreads();
        for (int ofs = 1; ofs < 1024; ofs <<= 1) {
            int t = (tid >= ofs) ? sdata[tid - ofs] : 0;
            __syncthreads();
            sdata[tid] += t;
            __syncthreads();
        }
        int excl = sdata[tid] - v + carry;
        if (i < NN) { off[i] = excl; wp[i] = excl; }
        __syncthreads();
        if (tid == 1023) carry += sdata[1023];
        __syncthreads();
    }
    if (tid == 0) off[NN] = carry;   // == EAUG
}

// stores (src,dst) per CSR slot; no edge-id indirection needed downstream
__global__ __launch_bounds__(256) void scatter_kernel(const int* __restrict__ ei,
                                                      int* __restrict__ wp,
                                                      int* __restrict__ csr_s,
                                                      int* __restrict__ csr_c) {
    int e = blockIdx.x * 256 + threadIdx.x;
    if (e >= EAUG) return;
    int r, c;
    if (e < NE) { r = ei[e]; c = ei[NE + e]; } else { r = c = e - NE; }
    int pos = atomicAdd(&wp[c], 1);
    csr_s[pos] = r;
    csr_c[pos] = c;
}

// ---------------------------------------------------------------- MFMA GEMM: O_m = A @ W_m^T (+bias)
// BFMASK bit m: output m stored as bf16 (ushort), else fp32.
template <int NM, int BFMASK>
__global__ __launch_bounds__(256) void gemm_mfma(
    const float* __restrict__ A, int nrows,
    const float* __restrict__ W0, const float* __restrict__ B0, void* __restrict__ O0,
    const float* __restrict__ W1, const float* __restrict__ B1, void* __restrict__ O1,
    const float* __restrict__ W2, const float* __restrict__ B2, void* __restrict__ O2,
    const float* __restrict__ W3, const float* __restrict__ B3, void* __restrict__ O3) {
    __shared__ __align__(16) unsigned short As[64 * LDA];
    __shared__ __align__(16) unsigned short Bs_lds[128 * LDA];
    const int t = threadIdx.x;
    const int r0 = blockIdx.x * 64;

    {   // stage A tile (fp32 -> bf16)
        const float4* A4 = (const float4*)A;
#pragma unroll
        for (int i = 0; i < 8; i++) {
            int f4 = t + i * 256;
            int row = f4 >> 5, q = f4 & 31;
            float4 v = make_float4(0.f, 0.f, 0.f, 0.f);
            if (r0 + row < nrows) v = A4[(size_t)(r0 + row) * 32 + q];
            ushort4 b;
            b.x = f2bf(v.x); b.y = f2bf(v.y); b.z = f2bf(v.z); b.w = f2bf(v.w);
            *(ushort4*)&As[row * LDA + q * 4] = b;
        }
    }

    const float* Ws[4] = {W0, W1, W2, W3};
    const float* Bb[4] = {B0, B1, B2, B3};
    void* Os[4] = {O0, O1, O2, O3};
    const int wv = t >> 6;
    const int ln = t & 63;
    const int lrow = ln & 15;
    const int lk = ln >> 4;

#pragma unroll
    for (int m = 0; m < NM; m++) {
        __syncthreads();
        {
            const float4* Wm4 = (const float4*)Ws[m];
#pragma unroll
            for (int i = 0; i < 16; i++) {
                int f4 = t + i * 256;
                int c = f4 >> 5, q = f4 & 31;
                float4 v = Wm4[f4];
                ushort4 b;
                b.x = f2bf(v.x); b.y = f2bf(v.y); b.z = f2bf(v.z); b.w = f2bf(v.w);
                *(ushort4*)&Bs_lds[c * LDA + q * 4] = b;
            }
        }
        __syncthreads();

        f32x4 acc[8];
#pragma unroll
        for (int nt = 0; nt < 8; nt++) acc[nt] = (f32x4){0.f, 0.f, 0.f, 0.f};

#pragma unroll
        for (int ks = 0; ks < 4; ks++) {
            int kb = ks * 32 + lk * 8;
            bf16x8 af = *(const bf16x8*)&As[(wv * 16 + lrow) * LDA + kb];
#pragma unroll
            for (int nt = 0; nt < 8; nt++) {
                bf16x8 bfr = *(const bf16x8*)&Bs_lds[(nt * 16 + lrow) * LDA + kb];
                acc[nt] = __builtin_amdgcn_mfma_f32_16x16x32_bf16(af, bfr, acc[nt], 0, 0, 0);
            }
        }

        const float* bias = Bb[m];
#pragma unroll
        for (int nt = 0; nt < 8; nt++) {
            int col = nt * 16 + lrow;
            float bv = bias ? bias[col] : 0.f;
#pragma unroll
            for (int j = 0; j < 4; j++) {
                int row = r0 + wv * 16 + lk * 4 + j;
                if (row < nrows) {
                    float val = acc[nt][j] + bv;
                    if ((BFMASK >> m) & 1)
                        ((unsigned short*)Os[m])[(size_t)row * HD + col] = f2bf(val);
                    else
                        ((float*)Os[m])[(size_t)row * HD + col] = val;
                }
            }
        }
    }
}

// ---------------------------------------------------------------- batchnorm
__global__ __launch_bounds__(256) void bn_reduce(const float* __restrict__ X,
                                                 float* __restrict__ sums) {
    int f = threadIdx.x & 127;
    int half = threadIdx.x >> 7;
    float s1 = 0.f, s2 = 0.f;
    for (int r = blockIdx.x * 2 + half; r < NN; r += gridDim.x * 2) {
        float v = X[(size_t)r * HD + f];
        s1 += v;
        s2 += v * v;
    }
    __shared__ float sm[512];
    sm[threadIdx.x] = s1;
    sm[256 + threadIdx.x] = s2;
    __syncthreads();
    if (half == 0) {
        atomicAdd(&sums[f], sm[f] + sm[128 + f]);
        atomicAdd(&sums[128 + f], sm[256 + f] + sm[256 + 128 + f]);
    }
}

__global__ __launch_bounds__(256) void bn_apply(const float* __restrict__ in,
                                                const float* __restrict__ sums,
                                                const float* __restrict__ gamma,
                                                const float* __restrict__ beta,
                                                const float* __restrict__ resid,
                                                float* __restrict__ out) {
    int idx = blockIdx.x * 256 + threadIdx.x;
    int f4 = idx & 31;
    float4 s1 = ((const float4*)sums)[f4];
    float4 s2 = ((const float4*)sums)[32 + f4];
    float4 g = ((const float4*)gamma)[f4];
    float4 bt = ((const float4*)beta)[f4];
    float4 v = ((const float4*)in)[idx];
    const float invn = 1.f / (float)NN;
    float4 o;
#define BN1(comp)                                                          \
    {                                                                      \
        float mean = s1.comp * invn;                                       \
        float var = s2.comp * invn - mean * mean;                          \
        float y = g.comp * (v.comp - mean) * rsqrtf(var + BN_EPS) + bt.comp; \
        o.comp = fmaxf(y, 0.f);                                            \
    }
    BN1(x) BN1(y) BN1(z) BN1(w)
#undef BN1
    if (resid) {
        float4 rv = ((const float4*)resid)[idx];
        o.x += rv.x; o.y += rv.y; o.z += rv.z; o.w += rv.w;
    }
    ((float4*)out)[idx] = o;
}

// ---------------------------------------------------------------- per-node dots from bf16 xg
__global__ __launch_bounds__(256) void node_dots(const unsigned short* __restrict__ xgb,
                                                 const float* __restrict__ Wh,
                                                 float* __restrict__ ar,
                                                 float* __restrict__ ac) {
    int wid = (blockIdx.x * 256 + threadIdx.x) >> 6;
    int l = threadIdx.x & 63;
    if (wid >= NN) return;
    unsigned int u = ((const unsigned int*)(xgb + (size_t)wid * HD))[l];
    float fx = b2f_lo(u), fy = b2f_hi(u);
    float2 wa = ((const float2*)Wh)[l];
    float2 wb = ((const float2*)Wh)[64 + l];
    float pa = fx * wa.x + fy * wa.y;
    float pb = fx * wb.x + fy * wb.y;
#pragma unroll
    for (int ofs = 1; ofs < 64; ofs <<= 1) {
        pa += __shfl_xor(pa, ofs);
        pb += __shfl_xor(pb, ofs);
    }
    if (l == 0) { ar[wid] = pa; ac[wid] = pb; }
}

// ---------------------------------------------------------------- edge pass (CSR order): s_ij -> exp terms + z sums
__global__ __launch_bounds__(256) void edge_pass(const unsigned short* __restrict__ xgb,
                                                 const float* __restrict__ ar,
                                                 const float* __restrict__ ac,
                                                 const int* __restrict__ csr_s,
                                                 const int* __restrict__ csr_c,
                                                 const float* __restrict__ bh,
                                                 float* __restrict__ econ,
                                                 float* __restrict__ edis,
                                                 float* __restrict__ zcon,
                                                 float* __restrict__ zdis) {
    int gid = blockIdx.x * 256 + threadIdx.x;
    int e = gid >> 4;   // CSR slot; 16 lanes per edge
    int l = gid & 15;
    if (e >= EAUG) return;
    int r = csr_s[e];
    int c = csr_c[e];   // consecutive slots share c -> xgb[c] row stays cache-hot
    const uint4* xr4 = (const uint4*)(xgb + (size_t)r * HD);
    const uint4* xc4 = (const uint4*)(xgb + (size_t)c * HD);
    uint4 ur = xr4[l], uc = xc4[l];
    float d, ss = 0.f;
    d = b2f_lo(ur.x) - b2f_lo(uc.x); ss += d * d;
    d = b2f_hi(ur.x) - b2f_hi(uc.x); ss += d * d;
    d = b2f_lo(ur.y) - b2f_lo(uc.y); ss += d * d;
    d = b2f_hi(ur.y) - b2f_hi(uc.y); ss += d * d;
    d = b2f_lo(ur.z) - b2f_lo(uc.z); ss += d * d;
    d = b2f_hi(ur.z) - b2f_hi(uc.z); ss += d * d;
    d = b2f_lo(ur.w) - b2f_lo(uc.w); ss += d * d;
    d = b2f_hi(ur.w) - b2f_hi(uc.w); ss += d * d;
#pragma unroll
    for (int ofs = 1; ofs < 16; ofs <<= 1) ss += __shfl_xor(ss, ofs);
    if (l == 0) {
        float g = sqrtf(ss + 1e-12f);
        float hh = softplusf(ar[r] + ac[c] + bh[0]);
        float tt = g + hh;                       // >= 0
        float s = 1.f / (1.f + expf(tt));        // sigmoid(-t), in (0, 0.5]
        float ec = expf(s);
        float ed = expf(1.f - s);
        econ[e] = ec;                            // sequential (CSR order)
        edis[e] = ed;
        atomicAdd(&zcon[r], ec);
        atomicAdd(&zdis[r], ed);
    }
}

// ---------------------------------------------------------------- aggregation + gating (+optional residual)
// w = e[j] / z[src]; econ/edis read sequentially, xcon/xdis gathered as bf16
__global__ __launch_bounds__(256) void agg_gate(const unsigned short* __restrict__ xcon,
                                                const unsigned short* __restrict__ xdis,
                                                const float* __restrict__ xself,
                                                const float* __restrict__ econ,
                                                const float* __restrict__ edis,
                                                const float* __restrict__ zcon,
                                                const float* __restrict__ zdis,
                                                const int* __restrict__ coff,
                                                const int* __restrict__ csr_s,
                                                const float* __restrict__ Wgate,
                                                const float* __restrict__ bgate,
                                                const float* __restrict__ resid,
                                                float* __restrict__ out) {
    int v = (blockIdx.x * 256 + threadIdx.x) >> 6;
    int l = threadIdx.x & 63;
    if (v >= NN) return;
    int beg = coff[v], end = coff[v + 1];
    float cx = 0.f, cy = 0.f, dxv = 0.f, dyv = 0.f;
    for (int j = beg; j < end; j++) {
        int r = csr_s[j];
        float wc = econ[j] / zcon[r];
        float wd = edis[j] / zdis[r];
        unsigned int ua = ((const unsigned int*)(xcon + (size_t)r * HD))[l];
        unsigned int ub = ((const unsigned int*)(xdis + (size_t)r * HD))[l];
        cx += wc * b2f_lo(ua); cy += wc * b2f_hi(ua);
        dxv += wd * b2f_lo(ub); dyv += wd * b2f_hi(ub);
    }
    float2 sf = ((const float2*)(xself + (size_t)v * HD))[l];
    float p[3];
#pragma unroll
    for (int i = 0; i < 3; i++) {
        float2 wa = ((const float2*)(Wgate + i * 384))[l];
        float2 wb = ((const float2*)(Wgate + i * 384 + 128))[l];
        float2 wc2 = ((const float2*)(Wgate + i * 384 + 256))[l];
        p[i] = wa.x * cx + wa.y * cy + wb.x * dxv + wb.y * dyv + wc2.x * sf.x + wc2.y * sf.y;
    }
#pragma unroll
    for (int ofs = 1; ofs < 64; ofs <<= 1) {
        p[0] += __shfl_xor(p[0], ofs);
        p[1] += __shfl_xor(p[1], ofs);
        p[2] += __shfl_xor(p[2], ofs);
    }
    float l0 = p[0] + bgate[0], l1 = p[1] + bgate[1], l2 = p[2] + bgate[2];
    float mx = fmaxf(l0, fmaxf(l1, l2));
    float e0 = expf(l0 - mx), e1 = expf(l1 - mx), e2 = expf(l2 - mx);
    float inv = 1.f / (e0 + e1 + e2);
    float g0 = e0 * inv, g1 = e1 * inv, g2 = e2 * inv;
    float2 o;
    o.x = g0 * cx + g1 * dxv + g2 * sf.x;
    o.y = g0 * cy + g1 * dyv + g2 * sf.y;
    if (resid) {
        float2 rv = ((const float2*)(resid + (size_t)v * HD))[l];
        o.x += rv.x; o.y += rv.y;
    }
    ((float2*)(out + (size_t)v * HD))[l] = o;
}

// ---------------------------------------------------------------- classifier
__global__ __launch_bounds__(256) void cls_gemm(const float* __restrict__ X,
                                                const float* __restrict__ W,
                                                const float* __restrict__ b,
                                                float* __restrict__ out) {
    int wid = (blockIdx.x * 256 + threadIdx.x) >> 6;
    int l = threadIdx.x & 63;
    if (wid >= NN) return;
    float2 xv = ((const float2*)(X + (size_t)wid * HD))[l];
    float keep = 0.f;
#pragma unroll
    for (int c = 0; c < NC; c++) {
        float2 wv = ((const float2*)(W + (size_t)c * HD))[l];
        float pp = xv.x * wv.x + xv.y * wv.y;
#pragma unroll
        for (int ofs = 1; ofs < 64; ofs <<= 1) pp += __shfl_xor(pp, ofs);
        if (l == c) keep = pp;
    }
    if (l < NC) out[(size_t)wid * NC + l] = keep + b[l];
}

// ---------------------------------------------------------------- launcher
extern "C" void kernel_launch(void* const* d_in, const int* in_sizes, int n_in,
                              void* d_out, int out_size, void* d_ws, size_t ws_size,
                              hipStream_t stream) {
    const float* x = (const float*)d_in[0];
    const int* ei = (const int*)d_in[1];
    const float* mlp_W = (const float*)d_in[2];
    const float* mlp_b = (const float*)d_in[3];
    const float* mlp_gamma = (const float*)d_in[4];
    const float* mlp_beta = (const float*)d_in[5];
    const float* bn0_gamma = (const float*)d_in[6];
    const float* bn0_beta = (const float*)d_in[7];
    const float* cls_W = (const float*)d_in[8];
    const float* cls_b = (const float*)d_in[9];

    const size_t NF = (size_t)NN * HD;
    float* ws = (float*)d_ws;
    float* raw = ws;                               // fp32 conv raw / x2
    float* h0 = ws + NF;
    float* x1 = ws + 2 * NF;
    unsigned short* xgb = (unsigned short*)(ws + 3 * NF);    // bf16 [NN][128]
    unsigned short* xconb = (unsigned short*)(ws + 4 * NF);  // bf16
    unsigned short* xdisb = (unsigned short*)(ws + 5 * NF);  // bf16
    float* xself = ws + 6 * NF;                    // fp32
    float* ar = ws + 7 * NF;
    float* ac = ar + NN;
    float* econ = ac + NN;
    float* edis = econ + EAUG;
    float* zcon = edis + EAUG;
    float* zdis = zcon + NN;
    float* bnsums = zdis + NN;             // 256
    int* cnt = (int*)(bnsums + 256);       // NN
    int* coff = cnt + NN;                  // NN+1
    int* wp = coff + NN + 1;               // NN
    int* csr_s = wp + NN;                  // EAUG
    int* csr_c = csr_s + EAUG;             // EAUG

    const int EB = (EAUG + 255) / 256;     // 3321
    const int GB = (NN + 63) / 64;         // 782
    const int WB = NN / 4;                 // 12500
    const int EDGEB = EAUG * 16 / 256;     // 53125

    // ---- CSR by col
    hipMemsetAsync(cnt, 0, NN * sizeof(int), stream);
    hist_kernel<<<EB, 256, 0, stream>>>(ei, cnt);
    scan_kernel<<<1, 1024, 0, stream>>>(cnt, coff, wp);
    scatter_kernel<<<EB, 256, 0, stream>>>(ei, wp, csr_s, csr_c);

    // ---- input MLP + BN + relu (all fp32 out)
    gemm_mfma<1, 0><<<GB, 256, 0, stream>>>(x, NN, mlp_W, mlp_b, raw,
                                            nullptr, nullptr, nullptr,
                                            nullptr, nullptr, nullptr,
                                            nullptr, nullptr, nullptr);
    hipMemsetAsync(bnsums, 0, 256 * sizeof(float), stream);
    bn_reduce<<<256, 256, 0, stream>>>(raw, bnsums);
    bn_apply<<<(int)(NF / 4 / 256), 256, 0, stream>>>(raw, bnsums, mlp_gamma, mlp_beta,
                                                      nullptr, h0);

    for (int layer = 0; layer < 2; layer++) {
        const float* Wg = (const float*)d_in[10 + layer * 9 + 0];
        const float* Wh = (const float*)d_in[10 + layer * 9 + 1];
        const float* bh = (const float*)d_in[10 + layer * 9 + 2];
        const float* Wcon = (const float*)d_in[10 + layer * 9 + 3];
        const float* Wdis = (const float*)d_in[10 + layer * 9 + 4];
        const float* Wself = (const float*)d_in[10 + layer * 9 + 5];
        const float* bself = (const float*)d_in[10 + layer * 9 + 6];
        const float* Wgate = (const float*)d_in[10 + layer * 9 + 7];
        const float* bgate = (const float*)d_in[10 + layer * 9 + 8];
        const float* hin = (layer == 0) ? h0 : x1;

        // xg/xcon/xdis stored bf16 (gathered downstream); xself fp32
        gemm_mfma<4, 0b0111><<<GB, 256, 0, stream>>>(hin, NN,
                                                     Wg, nullptr, xgb,
                                                     Wcon, nullptr, xconb,
                                                     Wdis, nullptr, xdisb,
                                                     Wself, bself, xself);
        node_dots<<<WB, 256, 0, stream>>>(xgb, Wh, ar, ac);
        hipMemsetAsync(zcon, 0, NN * sizeof(float), stream);
        hipMemsetAsync(zdis, 0, NN * sizeof(float), stream);
        edge_pass<<<EDGEB, 256, 0, stream>>>(xgb, ar, ac, csr_s, csr_c, bh,
                                             econ, edis, zcon, zdis);
        if (layer == 0) {
            agg_gate<<<WB, 256, 0, stream>>>(xconb, xdisb, xself, econ, edis, zcon, zdis,
                                             coff, csr_s, Wgate, bgate, nullptr, raw);
            hipMemsetAsync(bnsums, 0, 256 * sizeof(float), stream);
            bn_reduce<<<256, 256, 0, stream>>>(raw, bnsums);
            bn_apply<<<(int)(NF / 4 / 256), 256, 0, stream>>>(raw, bnsums, bn0_gamma,
                                                              bn0_beta, h0, x1);
        } else {
            agg_gate<<<WB, 256, 0, stream>>>(xconb, xdisb, xself, econ, edis, zcon, zdis,
                                             coff, csr_s, Wgate, bgate, x1, raw);
        }
    }

    // ---- classifier
    cls_gemm<<<WB, 256, 0, stream>>>(raw, cls_W, cls_b, (float*)d_out);
}

// Round 12
// 988.854 us; speedup vs baseline: 1.6168x; 1.1160x over previous
//
#include <hip/hip_runtime.h>
#include <math.h>

#define NN 50000
#define NE 800000
#define EAUG (NE + NN)
#define HD 128
#define NC 40
#define BN_EPS 1e-5f
#define LDA 136  // padded LDS stride (elems): 272B/row -> 2-way bank aliasing (free)

typedef short bf16x8 __attribute__((ext_vector_type(8)));
typedef float f32x4 __attribute__((ext_vector_type(4)));

// ---------------------------------------------------------------- utilities
static __device__ __forceinline__ float softplusf(float z) {
    if (z > 20.f) return z;
    if (z < -20.f) return expf(z);
    return log1pf(expf(z));
}

static __device__ __forceinline__ unsigned short f2bf(float f) {
    union { float f; unsigned int u; } v;
    v.f = f;
    unsigned int u = v.u;
    unsigned int r = (u + 0x7fffu + ((u >> 16) & 1u)) >> 16;
    return (unsigned short)r;
}
static __device__ __forceinline__ float b2f_lo(unsigned int u) {
    union { unsigned int i; float f; } v; v.i = u << 16; return v.f;
}
static __device__ __forceinline__ float b2f_hi(unsigned int u) {
    union { unsigned int i; float f; } v; v.i = u & 0xffff0000u; return v.f;
}

// ---------------------------------------------------------------- CSR build
__global__ __launch_bounds__(256) void hist_kernel(const int* __restrict__ ei,
                                                   int* __restrict__ cnt) {
    int e = blockIdx.x * 256 + threadIdx.x;
    if (e >= EAUG) return;
    int c = (e < NE) ? ei[NE + e] : (e - NE);
    atomicAdd(&cnt[c], 1);
}

__global__ __launch_bounds__(1024) void scan_kernel(const int* __restrict__ cnt,
                                                    int* __restrict__ off,
                                                    int* __restrict__ wp) {
    __shared__ int sdata[1024];
    __shared__ int carry;
    int tid = threadIdx.x;
    if (tid == 0) carry = 0;
    __syncthreads();
    for (int base = 0; base < NN; base += 1024) {
        int i = base + tid;
        int v = (i < NN) ? cnt[i] : 0;
        sdata[tid] = v;
        __syncthreads();
        for (int ofs = 1; ofs < 1024; ofs <<= 1) {
            int t = (tid >= ofs) ? sdata[tid - ofs] : 0;
            __syncthreads();
            sdata[tid] += t;
            __syncthreads();
        }
        int excl = sdata[tid] - v + carry;
        if (i < NN) { off[i] = excl; wp[i] = excl; }
        __syncthreads();
        if (tid == 1023) carry += sdata[1023];
        __syncthreads();
    }
    if (tid == 0) off[NN] = carry;   // == EAUG
}

// stores (src,dst) per CSR slot; no edge-id indirection needed downstream
__global__ __launch_bounds__(256) void scatter_kernel(const int* __restrict__ ei,
                                                      int* __restrict__ wp,
                                                      int* __restrict__ csr_s,
                                                      int* __restrict__ csr_c) {
    int e = blockIdx.x * 256 + threadIdx.x;
    if (e >= EAUG) return;
    int r, c;
    if (e < NE) { r = ei[e]; c = ei[NE + e]; } else { r = c = e - NE; }
    int pos = atomicAdd(&wp[c], 1);
    csr_s[pos] = r;
    csr_c[pos] = c;
}

// ---------------------------------------------------------------- MFMA GEMM: O_m = A @ W_m^T (+bias)
// BFMASK bit m: output m stored as bf16 (ushort), else fp32.
template <int NM, int BFMASK>
__global__ __launch_bounds__(256) void gemm_mfma(
    const float* __restrict__ A, int nrows,
    const float* __restrict__ W0, const float* __restrict__ B0, void* __restrict__ O0,
    const float* __restrict__ W1, const float* __restrict__ B1, void* __restrict__ O1,
    const float* __restrict__ W2, const float* __restrict__ B2, void* __restrict__ O2,
    const float* __restrict__ W3, const float* __restrict__ B3, void* __restrict__ O3) {
    __shared__ __align__(16) unsigned short As[64 * LDA];
    __shared__ __align__(16) unsigned short Bs_lds[128 * LDA];
    const int t = threadIdx.x;
    const int r0 = blockIdx.x * 64;

    {   // stage A tile (fp32 -> bf16)
        const float4* A4 = (const float4*)A;
#pragma unroll
        for (int i = 0; i < 8; i++) {
            int f4 = t + i * 256;
            int row = f4 >> 5, q = f4 & 31;
            float4 v = make_float4(0.f, 0.f, 0.f, 0.f);
            if (r0 + row < nrows) v = A4[(size_t)(r0 + row) * 32 + q];
            ushort4 b;
            b.x = f2bf(v.x); b.y = f2bf(v.y); b.z = f2bf(v.z); b.w = f2bf(v.w);
            *(ushort4*)&As[row * LDA + q * 4] = b;
        }
    }

    const float* Ws[4] = {W0, W1, W2, W3};
    const float* Bb[4] = {B0, B1, B2, B3};
    void* Os[4] = {O0, O1, O2, O3};
    const int wv = t >> 6;
    const int ln = t & 63;
    const int lrow = ln & 15;
    const int lk = ln >> 4;

#pragma unroll
    for (int m = 0; m < NM; m++) {
        __syncthreads();
        {
            const float4* Wm4 = (const float4*)Ws[m];
#pragma unroll
            for (int i = 0; i < 16; i++) {
                int f4 = t + i * 256;
                int c = f4 >> 5, q = f4 & 31;
                float4 v = Wm4[f4];
                ushort4 b;
                b.x = f2bf(v.x); b.y = f2bf(v.y); b.z = f2bf(v.z); b.w = f2bf(v.w);
                *(ushort4*)&Bs_lds[c * LDA + q * 4] = b;
            }
        }
        __syncthreads();

        f32x4 acc[8];
#pragma unroll
        for (int nt = 0; nt < 8; nt++) acc[nt] = (f32x4){0.f, 0.f, 0.f, 0.f};

#pragma unroll
        for (int ks = 0; ks < 4; ks++) {
            int kb = ks * 32 + lk * 8;
            bf16x8 af = *(const bf16x8*)&As[(wv * 16 + lrow) * LDA + kb];
#pragma unroll
            for (int nt = 0; nt < 8; nt++) {
                bf16x8 bfr = *(const bf16x8*)&Bs_lds[(nt * 16 + lrow) * LDA + kb];
                acc[nt] = __builtin_amdgcn_mfma_f32_16x16x32_bf16(af, bfr, acc[nt], 0, 0, 0);
            }
        }

        const float* bias = Bb[m];
#pragma unroll
        for (int nt = 0; nt < 8; nt++) {
            int col = nt * 16 + lrow;
            float bv = bias ? bias[col] : 0.f;
#pragma unroll
            for (int j = 0; j < 4; j++) {
                int row = r0 + wv * 16 + lk * 4 + j;
                if (row < nrows) {
                    float val = acc[nt][j] + bv;
                    if ((BFMASK >> m) & 1)
                        ((unsigned short*)Os[m])[(size_t)row * HD + col] = f2bf(val);
                    else
                        ((float*)Os[m])[(size_t)row * HD + col] = val;
                }
            }
        }
    }
}

// ---------------------------------------------------------------- batchnorm
__global__ __launch_bounds__(256) void bn_reduce(const float* __restrict__ X,
                                                 float* __restrict__ sums) {
    int f = threadIdx.x & 127;
    int half = threadIdx.x >> 7;
    float s1 = 0.f, s2 = 0.f;
    for (int r = blockIdx.x * 2 + half; r < NN; r += gridDim.x * 2) {
        float v = X[(size_t)r * HD + f];
        s1 += v;
        s2 += v * v;
    }
    __shared__ float sm[512];
    sm[threadIdx.x] = s1;
    sm[256 + threadIdx.x] = s2;
    __syncthreads();
    if (half == 0) {
        atomicAdd(&sums[f], sm[f] + sm[128 + f]);
        atomicAdd(&sums[128 + f], sm[256 + f] + sm[256 + 128 + f]);
    }
}

__global__ __launch_bounds__(256) void bn_apply(const float* __restrict__ in,
                                                const float* __restrict__ sums,
                                                const float* __restrict__ gamma,
                                                const float* __restrict__ beta,
                                                const float* __restrict__ resid,
                                                float* __restrict__ out) {
    int idx = blockIdx.x * 256 + threadIdx.x;
    int f4 = idx & 31;
    float4 s1 = ((const float4*)sums)[f4];
    float4 s2 = ((const float4*)sums)[32 + f4];
    float4 g = ((const float4*)gamma)[f4];
    float4 bt = ((const float4*)beta)[f4];
    float4 v = ((const float4*)in)[idx];
    const float invn = 1.f / (float)NN;
    float4 o;
#define BN1(comp)                                                          \
    {                                                                      \
        float mean = s1.comp * invn;                                       \
        float var = s2.comp * invn - mean * mean;                          \
        float y = g.comp * (v.comp - mean) * rsqrtf(var + BN_EPS) + bt.comp; \
        o.comp = fmaxf(y, 0.f);                                            \
    }
    BN1(x) BN1(y) BN1(z) BN1(w)
#undef BN1
    if (resid) {
        float4 rv = ((const float4*)resid)[idx];
        o.x += rv.x; o.y += rv.y; o.z += rv.z; o.w += rv.w;
    }
    ((float4*)out)[idx] = o;
}

// ---------------------------------------------------------------- per-node dots from bf16 xg
__global__ __launch_bounds__(256) void node_dots(const unsigned short* __restrict__ xgb,
                                                 const float* __restrict__ Wh,
                                                 float* __restrict__ ar,
                                                 float* __restrict__ ac) {
    int wid = (blockIdx.x * 256 + threadIdx.x) >> 6;
    int l = threadIdx.x & 63;
    if (wid >= NN) return;
    unsigned int u = ((const unsigned int*)(xgb + (size_t)wid * HD))[l];
    float fx = b2f_lo(u), fy = b2f_hi(u);
    float2 wa = ((const float2*)Wh)[l];
    float2 wb = ((const float2*)Wh)[64 + l];
    float pa = fx * wa.x + fy * wa.y;
    float pb = fx * wb.x + fy * wb.y;
#pragma unroll
    for (int ofs = 1; ofs < 64; ofs <<= 1) {
        pa += __shfl_xor(pa, ofs);
        pb += __shfl_xor(pb, ofs);
    }
    if (l == 0) { ar[wid] = pa; ac[wid] = pb; }
}

// ---------------------------------------------------------------- edge pass (CSR order): s_ij -> exp terms + z sums
__global__ __launch_bounds__(256) void edge_pass(const unsigned short* __restrict__ xgb,
                                                 const float* __restrict__ ar,
                                                 const float* __restrict__ ac,
                                                 const int* __restrict__ csr_s,
                                                 const int* __restrict__ csr_c,
                                                 const float* __restrict__ bh,
                                                 float* __restrict__ econ,
                                                 float* __restrict__ edis,
                                                 float* __restrict__ zcon,
                                                 float* __restrict__ zdis) {
    int gid = blockIdx.x * 256 + threadIdx.x;
    int e = gid >> 4;   // CSR slot; 16 lanes per edge
    int l = gid & 15;
    if (e >= EAUG) return;
    int r = csr_s[e];
    int c = csr_c[e];   // consecutive slots share c -> xgb[c] row stays cache-hot
    const uint4* xr4 = (const uint4*)(xgb + (size_t)r * HD);
    const uint4* xc4 = (const uint4*)(xgb + (size_t)c * HD);
    uint4 ur = xr4[l], uc = xc4[l];
    float d, ss = 0.f;
    d = b2f_lo(ur.x) - b2f_lo(uc.x); ss += d * d;
    d = b2f_hi(ur.x) - b2f_hi(uc.x); ss += d * d;
    d = b2f_lo(ur.y) - b2f_lo(uc.y); ss += d * d;
    d = b2f_hi(ur.y) - b2f_hi(uc.y); ss += d * d;
    d = b2f_lo(ur.z) - b2f_lo(uc.z); ss += d * d;
    d = b2f_hi(ur.z) - b2f_hi(uc.z); ss += d * d;
    d = b2f_lo(ur.w) - b2f_lo(uc.w); ss += d * d;
    d = b2f_hi(ur.w) - b2f_hi(uc.w); ss += d * d;
#pragma unroll
    for (int ofs = 1; ofs < 16; ofs <<= 1) ss += __shfl_xor(ss, ofs);
    if (l == 0) {
        float g = sqrtf(ss + 1e-12f);
        float hh = softplusf(ar[r] + ac[c] + bh[0]);
        float tt = g + hh;                       // >= 0
        float s = 1.f / (1.f + expf(tt));        // sigmoid(-t), in (0, 0.5]
        float ec = expf(s);
        float ed = expf(1.f - s);
        econ[e] = ec;                            // sequential (CSR order)
        edis[e] = ed;
        atomicAdd(&zcon[r], ec);
        atomicAdd(&zdis[r], ed);
    }
}

// ---------------------------------------------------------------- aggregation + gating (+optional residual)
// w = e[j] / z[src]; econ/edis read sequentially, xcon/xdis gathered as bf16
__global__ __launch_bounds__(256) void agg_gate(const unsigned short* __restrict__ xcon,
                                                const unsigned short* __restrict__ xdis,
                                                const float* __restrict__ xself,
                                                const float* __restrict__ econ,
                                                const float* __restrict__ edis,
                                                const float* __restrict__ zcon,
                                                const float* __restrict__ zdis,
                                                const int* __restrict__ coff,
                                                const int* __restrict__ csr_s,
                                                const float* __restrict__ Wgate,
                                                const float* __restrict__ bgate,
                                                const float* __restrict__ resid,
                                                float* __restrict__ out) {
    int v = (blockIdx.x * 256 + threadIdx.x) >> 6;
    int l = threadIdx.x & 63;
    if (v >= NN) return;
    int beg = coff[v], end = coff[v + 1];
    float cx = 0.f, cy = 0.f, dxv = 0.f, dyv = 0.f;
    for (int j = beg; j < end; j++) {
        int r = csr_s[j];
        float wc = econ[j] / zcon[r];
        float wd = edis[j] / zdis[r];
        unsigned int ua = ((const unsigned int*)(xcon + (size_t)r * HD))[l];
        unsigned int ub = ((const unsigned int*)(xdis + (size_t)r * HD))[l];
        cx += wc * b2f_lo(ua); cy += wc * b2f_hi(ua);
        dxv += wd * b2f_lo(ub); dyv += wd * b2f_hi(ub);
    }
    float2 sf = ((const float2*)(xself + (size_t)v * HD))[l];
    float p[3];
#pragma unroll
    for (int i = 0; i < 3; i++) {
        float2 wa = ((const float2*)(Wgate + i * 384))[l];
        float2 wb = ((const float2*)(Wgate + i * 384 + 128))[l];
        float2 wc2 = ((const float2*)(Wgate + i * 384 + 256))[l];
        p[i] = wa.x * cx + wa.y * cy + wb.x * dxv + wb.y * dyv + wc2.x * sf.x + wc2.y * sf.y;
    }
#pragma unroll
    for (int ofs = 1; ofs < 64; ofs <<= 1) {
        p[0] += __shfl_xor(p[0], ofs);
        p[1] += __shfl_xor(p[1], ofs);
        p[2] += __shfl_xor(p[2], ofs);
    }
    float l0 = p[0] + bgate[0], l1 = p[1] + bgate[1], l2 = p[2] + bgate[2];
    float mx = fmaxf(l0, fmaxf(l1, l2));
    float e0 = expf(l0 - mx), e1 = expf(l1 - mx), e2 = expf(l2 - mx);
    float inv = 1.f / (e0 + e1 + e2);
    float g0 = e0 * inv, g1 = e1 * inv, g2 = e2 * inv;
    float2 o;
    o.x = g0 * cx + g1 * dxv + g2 * sf.x;
    o.y = g0 * cy + g1 * dyv + g2 * sf.y;
    if (resid) {
        float2 rv = ((const float2*)(resid + (size_t)v * HD))[l];
        o.x += rv.x; o.y += rv.y;
    }
    ((float2*)(out + (size_t)v * HD))[l] = o;
}

// ---------------------------------------------------------------- classifier via MFMA: out[N,40] = X @ W^T + b
// 64 rows/block; W [40][128] staged bf16, padded to 48 rows (3 col-tiles of 16).
__global__ __launch_bounds__(256) void cls_mfma(const float* __restrict__ X,
                                                const float* __restrict__ W,
                                                const float* __restrict__ b,
                                                float* __restrict__ out) {
    __shared__ __align__(16) unsigned short As[64 * LDA];
    __shared__ __align__(16) unsigned short Wsm[48 * LDA];
    const int t = threadIdx.x;
    const int r0 = blockIdx.x * 64;

    // zero the pad rows 40..47
    for (int i = t; i < 8 * LDA; i += 256) Wsm[40 * LDA + i] = 0;

    {   // stage X rows (fp32 -> bf16)
        const float4* A4 = (const float4*)X;
#pragma unroll
        for (int i = 0; i < 8; i++) {
            int f4 = t + i * 256;
            int row = f4 >> 5, q = f4 & 31;
            float4 v = make_float4(0.f, 0.f, 0.f, 0.f);
            if (r0 + row < NN) v = A4[(size_t)(r0 + row) * 32 + q];
            ushort4 bb;
            bb.x = f2bf(v.x); bb.y = f2bf(v.y); bb.z = f2bf(v.z); bb.w = f2bf(v.w);
            *(ushort4*)&As[row * LDA + q * 4] = bb;
        }
    }
    {   // stage W [40][128]: 1280 float4s = 5 iters exactly
        const float4* W4 = (const float4*)W;
#pragma unroll
        for (int i = 0; i < 5; i++) {
            int f4 = t + i * 256;          // 0..1279
            int c = f4 >> 5, q = f4 & 31;  // c: 0..39
            float4 v = W4[f4];
            ushort4 bb;
            bb.x = f2bf(v.x); bb.y = f2bf(v.y); bb.z = f2bf(v.z); bb.w = f2bf(v.w);
            *(ushort4*)&Wsm[c * LDA + q * 4] = bb;
        }
    }
    __syncthreads();

    const int wv = t >> 6;
    const int ln = t & 63;
    const int lrow = ln & 15;
    const int lk = ln >> 4;

    f32x4 acc[3];
#pragma unroll
    for (int nt = 0; nt < 3; nt++) acc[nt] = (f32x4){0.f, 0.f, 0.f, 0.f};

#pragma unroll
    for (int ks = 0; ks < 4; ks++) {
        int kb = ks * 32 + lk * 8;
        bf16x8 af = *(const bf16x8*)&As[(wv * 16 + lrow) * LDA + kb];
#pragma unroll
        for (int nt = 0; nt < 3; nt++) {
            bf16x8 bfr = *(const bf16x8*)&Wsm[(nt * 16 + lrow) * LDA + kb];
            acc[nt] = __builtin_amdgcn_mfma_f32_16x16x32_bf16(af, bfr, acc[nt], 0, 0, 0);
        }
    }

#pragma unroll
    for (int nt = 0; nt < 3; nt++) {
        int col = nt * 16 + lrow;
        if (col < NC) {
            float bv = b[col];
#pragma unroll
            for (int j = 0; j < 4; j++) {
                int row = r0 + wv * 16 + lk * 4 + j;
                if (row < NN) out[(size_t)row * NC + col] = acc[nt][j] + bv;
            }
        }
    }
}

// ---------------------------------------------------------------- launcher
extern "C" void kernel_launch(void* const* d_in, const int* in_sizes, int n_in,
                              void* d_out, int out_size, void* d_ws, size_t ws_size,
                              hipStream_t stream) {
    const float* x = (const float*)d_in[0];
    const int* ei = (const int*)d_in[1];
    const float* mlp_W = (const float*)d_in[2];
    const float* mlp_b = (const float*)d_in[3];
    const float* mlp_gamma = (const float*)d_in[4];
    const float* mlp_beta = (const float*)d_in[5];
    const float* bn0_gamma = (const float*)d_in[6];
    const float* bn0_beta = (const float*)d_in[7];
    const float* cls_W = (const float*)d_in[8];
    const float* cls_b = (const float*)d_in[9];

    const size_t NF = (size_t)NN * HD;
    float* ws = (float*)d_ws;
    float* raw = ws;                               // fp32 conv raw / x2
    float* h0 = ws + NF;
    float* x1 = ws + 2 * NF;
    unsigned short* xgb = (unsigned short*)(ws + 3 * NF);    // bf16 [NN][128]
    unsigned short* xconb = (unsigned short*)(ws + 4 * NF);  // bf16
    unsigned short* xdisb = (unsigned short*)(ws + 5 * NF);  // bf16
    float* xself = ws + 6 * NF;                    // fp32
    float* ar = ws + 7 * NF;
    float* ac = ar + NN;
    float* econ = ac + NN;
    float* edis = econ + EAUG;
    float* zcon = edis + EAUG;
    float* zdis = zcon + NN;
    float* bnsums = zdis + NN;             // 256
    int* cnt = (int*)(bnsums + 256);       // NN
    int* coff = cnt + NN;                  // NN+1
    int* wp = coff + NN + 1;               // NN
    int* csr_s = wp + NN;                  // EAUG
    int* csr_c = csr_s + EAUG;             // EAUG

    const int EB = (EAUG + 255) / 256;     // 3321
    const int GB = (NN + 63) / 64;         // 782
    const int WB = NN / 4;                 // 12500
    const int EDGEB = EAUG * 16 / 256;     // 53125

    // ---- CSR by col
    hipMemsetAsync(cnt, 0, NN * sizeof(int), stream);
    hist_kernel<<<EB, 256, 0, stream>>>(ei, cnt);
    scan_kernel<<<1, 1024, 0, stream>>>(cnt, coff, wp);
    scatter_kernel<<<EB, 256, 0, stream>>>(ei, wp, csr_s, csr_c);

    // ---- input MLP + BN + relu (all fp32 out)
    gemm_mfma<1, 0><<<GB, 256, 0, stream>>>(x, NN, mlp_W, mlp_b, raw,
                                            nullptr, nullptr, nullptr,
                                            nullptr, nullptr, nullptr,
                                            nullptr, nullptr, nullptr);
    hipMemsetAsync(bnsums, 0, 256 * sizeof(float), stream);
    bn_reduce<<<256, 256, 0, stream>>>(raw, bnsums);
    bn_apply<<<(int)(NF / 4 / 256), 256, 0, stream>>>(raw, bnsums, mlp_gamma, mlp_beta,
                                                      nullptr, h0);

    for (int layer = 0; layer < 2; layer++) {
        const float* Wg = (const float*)d_in[10 + layer * 9 + 0];
        const float* Wh = (const float*)d_in[10 + layer * 9 + 1];
        const float* bh = (const float*)d_in[10 + layer * 9 + 2];
        const float* Wcon = (const float*)d_in[10 + layer * 9 + 3];
        const float* Wdis = (const float*)d_in[10 + layer * 9 + 4];
        const float* Wself = (const float*)d_in[10 + layer * 9 + 5];
        const float* bself = (const float*)d_in[10 + layer * 9 + 6];
        const float* Wgate = (const float*)d_in[10 + layer * 9 + 7];
        const float* bgate = (const float*)d_in[10 + layer * 9 + 8];
        const float* hin = (layer == 0) ? h0 : x1;

        // xg/xcon/xdis stored bf16 (gathered downstream); xself fp32
        gemm_mfma<4, 0b0111><<<GB, 256, 0, stream>>>(hin, NN,
                                                     Wg, nullptr, xgb,
                                                     Wcon, nullptr, xconb,
                                                     Wdis, nullptr, xdisb,
                                                     Wself, bself, xself);
        node_dots<<<WB, 256, 0, stream>>>(xgb, Wh, ar, ac);
        hipMemsetAsync(zcon, 0, NN * sizeof(float), stream);
        hipMemsetAsync(zdis, 0, NN * sizeof(float), stream);
        edge_pass<<<EDGEB, 256, 0, stream>>>(xgb, ar, ac, csr_s, csr_c, bh,
                                             econ, edis, zcon, zdis);
        if (layer == 0) {
            agg_gate<<<WB, 256, 0, stream>>>(xconb, xdisb, xself, econ, edis, zcon, zdis,
                                             coff, csr_s, Wgate, bgate, nullptr, raw);
            hipMemsetAsync(bnsums, 0, 256 * sizeof(float), stream);
            bn_reduce<<<256, 256, 0, stream>>>(raw, bnsums);
            bn_apply<<<(int)(NF / 4 / 256), 256, 0, stream>>>(raw, bnsums, bn0_gamma,
                                                              bn0_beta, h0, x1);
        } else {
            agg_gate<<<WB, 256, 0, stream>>>(xconb, xdisb, xself, econ, edis, zcon, zdis,
                                             coff, csr_s, Wgate, bgate, x1, raw);
        }
    }

    // ---- classifier (MFMA)
    cls_mfma<<<GB, 256, 0, stream>>>(raw, cls_W, cls_b, (float*)d_out);
}